// Round 1
// baseline (299.899 us; speedup 1.0000x reference)
//
#include <hip/hip_runtime.h>
#include <math.h>

#define NBOX 21840
#define NPAD 22528   // 11 * 2048, also 88*256
#define NSEG 11
#define SEGSZ 2048
#define BATCH 32
#define NCLS 21
#define NEGV -1e30f

__device__ __forceinline__ bool prec(float sa, int ia, float sb, int ib) {
    // true if (sa,ia) comes first in (score desc, idx asc) order
    return (sa > sb) || (sa == sb && ia < ib);
}

// ---------------- Kernel A: decode ----------------
__global__ __launch_bounds__(256) void decode_kernel(
    const float* __restrict__ y_pred, const float* __restrict__ box_tensor,
    float* __restrict__ X0, float* __restrict__ Y0, float* __restrict__ X1,
    float* __restrict__ Y1, float* __restrict__ CL, float* __restrict__ SS,
    int* __restrict__ SI)
{
    int i = blockIdx.x * 256 + threadIdx.x;
    int img = blockIdx.y;
    size_t o = (size_t)img * NPAD + i;
    if (i >= NBOX) {            // padding entries: never selectable
        X0[o] = 0.f; Y0[o] = 0.f; X1[o] = 0.f; Y1[o] = 0.f; CL[o] = 0.f;
        SS[o] = NEGV; SI[o] = i;
        return;
    }
    const float* yp = y_pred + ((size_t)img * NBOX + i) * 25;
    // argmax over 21 logits, first-index tie-break (matches jnp.argmax)
    float best = yp[0]; int bi = 0;
    #pragma unroll
    for (int k = 1; k < NCLS; k++) { float v = yp[k]; if (v > best) { best = v; bi = k; } }
    const float* a = box_tensor + (size_t)i * 4;
    float acx = a[0], acy = a[1], aw = a[2], ah = a[3];
    float t0 = yp[21], t1 = yp[22], t2 = yp[23], t3 = yp[24];
    // exact-op decode (no fma contraction; exp through double = correctly rounded f32)
    float cx = __fadd_rn(__fmul_rn(__fmul_rn(t0, 0.1f), aw), acx);
    float cy = __fadd_rn(__fmul_rn(__fmul_rn(t1, 0.1f), ah), acy);
    float w  = __fmul_rn((float)exp((double)__fmul_rn(t2, 0.2f)), aw);
    float h  = __fmul_rn((float)exp((double)__fmul_rn(t3, 0.2f)), ah);
    float hw = __fmul_rn(0.5f, w), hh = __fmul_rn(0.5f, h);
    float xmin = fminf(fmaxf(__fsub_rn(cx, hw), 0.f), 1.f);
    float ymin = fminf(fmaxf(__fsub_rn(cy, hh), 0.f), 1.f);
    float xmax = fminf(fmaxf(__fadd_rn(cx, hw), 0.f), 1.f);
    float ymax = fminf(fmaxf(__fadd_rn(cy, hh), 0.f), 1.f);
    bool valid = (bi != 0) && (best > 0.01f);
    X0[o] = xmin; Y0[o] = ymin; X1[o] = xmax; Y1[o] = ymax; CL[o] = (float)bi;
    SS[o] = valid ? best : NEGV;
    SI[o] = i;
}

// ---------------- Kernel B: per-segment bitonic sort of (score, idx) ----------------
__global__ __launch_bounds__(1024) void sort_kernel(float* __restrict__ SS, int* __restrict__ SI)
{
    __shared__ float ss[SEGSZ];
    __shared__ int   si[SEGSZ];
    int seg = blockIdx.x, img = blockIdx.y;
    size_t base = (size_t)img * NPAD + (size_t)seg * SEGSZ;
    int tid = threadIdx.x;
    ss[tid] = SS[base + tid];               si[tid] = SI[base + tid];
    ss[tid + 1024] = SS[base + tid + 1024]; si[tid + 1024] = SI[base + tid + 1024];
    for (int k = 2; k <= SEGSZ; k <<= 1) {
        for (int j = k >> 1; j > 0; j >>= 1) {
            __syncthreads();
            #pragma unroll
            for (int r = 0; r < 2; r++) {
                int e = tid + r * 1024;
                int l = e ^ j;
                if (l > e) {
                    float s1 = ss[e], s2 = ss[l];
                    int   i1 = si[e], i2 = si[l];
                    bool up = ((e & k) == 0);
                    bool sw = up ? prec(s2, i2, s1, i1) : prec(s1, i1, s2, i2);
                    if (sw) { ss[e] = s2; si[e] = i2; ss[l] = s1; si[l] = i1; }
                }
            }
        }
    }
    __syncthreads();
    SS[base + tid] = ss[tid];               SI[base + tid] = si[tid];
    SS[base + tid + 1024] = ss[tid + 1024]; SI[base + tid + 1024] = si[tid + 1024];
}

// ---------------- Kernel C: one wave per image, 11-way merge + greedy NMS ----------------
__global__ __launch_bounds__(64) void nms_kernel(
    const float* __restrict__ X0, const float* __restrict__ Y0,
    const float* __restrict__ X1, const float* __restrict__ Y1,
    const float* __restrict__ CL, const float* __restrict__ SS,
    const int* __restrict__ SI, float* __restrict__ out)
{
    int img = blockIdx.x, lane = threadIdx.x;
    const float* x0 = X0 + (size_t)img * NPAD;
    const float* y0 = Y0 + (size_t)img * NPAD;
    const float* x1 = X1 + (size_t)img * NPAD;
    const float* y1 = Y1 + (size_t)img * NPAD;
    const float* cl = CL + (size_t)img * NPAD;
    const float* ss = SS + (size_t)img * NPAD;
    const int*   si = SI + (size_t)img * NPAD;
    float* orow = out + (size_t)img * 600;

    // lane < NSEG owns a sorted segment; keep (cur, nxt) heads in registers
    float cur_s = NEGV, nxt_s = NEGV;
    int   cur_i = 0x7fffffff, nxt_i = 0x7fffffff;
    int   pos = 2;
    if (lane < NSEG) {
        cur_s = ss[lane * SEGSZ];     cur_i = si[lane * SEGSZ];
        nxt_s = ss[lane * SEGSZ + 1]; nxt_i = si[lane * SEGSZ + 1];
    }

    float ax0[2], ay0[2], ax1[2], ay1[2], aar[2];
    int A = 0;
    while (A < 100) {
        // wave-wide argmax of heads under (score desc, idx asc)
        float bs = cur_s; int bi = cur_i;
        #pragma unroll
        for (int off = 32; off > 0; off >>= 1) {
            float os = __shfl_xor(bs, off);
            int   oi = __shfl_xor(bi, off);
            if (prec(os, oi, bs, bi)) { bs = os; bi = oi; }
        }
        if (bs <= -1e29f) break;   // only NEG left -> remaining rows are zero

        // pop: owning lane advances, prefetch next
        if (lane < NSEG && cur_i == bi) {
            cur_s = nxt_s; cur_i = nxt_i;
            if (pos < SEGSZ) {
                nxt_s = ss[lane * SEGSZ + pos];
                nxt_i = si[lane * SEGSZ + pos];
                pos++;
            } else { nxt_s = NEGV; nxt_i = 0x7fffffff; }
        }

        // candidate box (broadcast load)
        float bx0 = x0[bi], by0 = y0[bi], bx1 = x1[bi], by1 = y1[bi];
        float barea = __fmul_rn(__fsub_rn(bx1, bx0), __fsub_rn(by1, by0));

        // check against accepted list (2 slots per lane)
        bool sup = false;
        #pragma unroll
        for (int t = 0; t < 2; t++) {
            int slot = lane + 64 * t;
            if (slot < A) {
                float ix1 = fmaxf(ax0[t], bx0);
                float iy1 = fmaxf(ay0[t], by0);
                float ix2 = fminf(ax1[t], bx1);
                float iy2 = fminf(ay1[t], by1);
                float inter = __fmul_rn(fmaxf(__fsub_rn(ix2, ix1), 0.f),
                                        fmaxf(__fsub_rn(iy2, iy1), 0.f));
                float uni = __fsub_rn(__fadd_rn(aar[t], barea), inter);
                float iou = (uni > 0.f) ? __fdiv_rn(inter, fmaxf(uni, 1e-12f)) : 0.f;
                if (iou > 0.45f) sup = true;
            }
        }
        if (__ballot(sup) == 0ull) {
            // accept
            if (lane == (A & 63)) {
                if ((A >> 6) == 0) { ax0[0]=bx0; ay0[0]=by0; ax1[0]=bx1; ay1[0]=by1; aar[0]=barea; }
                else               { ax0[1]=bx0; ay0[1]=by0; ax1[1]=bx1; ay1[1]=by1; aar[1]=barea; }
            }
            if (lane == 0) {
                orow[A * 6 + 0] = cl[bi];
                orow[A * 6 + 1] = bs;
                orow[A * 6 + 2] = bx0;
                orow[A * 6 + 3] = by0;
                orow[A * 6 + 4] = bx1;
                orow[A * 6 + 5] = by1;
            }
            A++;
        }
    }
    // zero-fill remaining rows
    for (int r = lane; r < (100 - A) * 6; r += 64) orow[A * 6 + r] = 0.f;
}

extern "C" void kernel_launch(void* const* d_in, const int* in_sizes, int n_in,
                              void* d_out, int out_size, void* d_ws, size_t ws_size,
                              hipStream_t stream)
{
    const float* y_pred     = (const float*)d_in[0];
    const float* box_tensor = (const float*)d_in[1];
    float* out = (float*)d_out;
    float* ws  = (float*)d_ws;

    size_t stride = (size_t)BATCH * NPAD;
    float* X0 = ws;
    float* Y0 = X0 + stride;
    float* X1 = Y0 + stride;
    float* Y1 = X1 + stride;
    float* CL = Y1 + stride;
    float* SS = CL + stride;
    int*   SI = (int*)(SS + stride);

    decode_kernel<<<dim3(NPAD / 256, BATCH), 256, 0, stream>>>(
        y_pred, box_tensor, X0, Y0, X1, Y1, CL, SS, SI);
    sort_kernel<<<dim3(NSEG, BATCH), 1024, 0, stream>>>(SS, SI);
    nms_kernel<<<BATCH, 64, 0, stream>>>(X0, Y0, X1, Y1, CL, SS, SI, out);
}

// Round 2
// 211.229 us; speedup vs baseline: 1.4198x; 1.4198x over previous
//
#include <hip/hip_runtime.h>
#include <math.h>

typedef unsigned long long ull;
typedef unsigned int uint;

#define NBOX 21840
#define NPAD 22528   // 11 * 2048 = 88 * 256
#define NSEG 11
#define SEGSZ 2048
#define BATCH 32
#define NCLS 21
#define NEGV -1e30f
#define PFX 372                 // per-segment prefix staged into the merge
#define MCAP 4096               // padded merge capacity (pow2)
#define NWALK (NSEG * PFX)      // 4092 real merged candidates

// ---- sortable key helpers: ascending u64 == (score desc, idx asc) ----
__device__ __forceinline__ uint key_hi(float s) {
    uint b = __float_as_uint(s);
    uint m = (uint)((int)b >> 31) | 0x80000000u;
    return ~(b ^ m);                       // valid (s>0.01) => hi < 0x80000000
}
__device__ __forceinline__ float key_score(uint hi) {
    uint srt = ~hi;
    uint b = (srt & 0x80000000u) ? (srt ^ 0x80000000u) : ~srt;
    return __uint_as_float(b);
}

// ---------------- Kernel A: decode (LDS-staged coalesced loads) ----------------
__global__ __launch_bounds__(256) void decode_kernel(
    const float* __restrict__ y_pred, const float* __restrict__ box_tensor,
    float* __restrict__ X0, float* __restrict__ Y0, float* __restrict__ X1,
    float* __restrict__ Y1, float* __restrict__ CL, ull* __restrict__ KS)
{
    __shared__ float st[256 * 25];
    int img = blockIdx.y;
    int b0  = blockIdx.x << 8;
    int tid = threadIdx.x;
    int nval = NBOX - b0; if (nval > 256) nval = 256;   // may be <= 0 (pad blocks)
    if (nval > 0) {
        const float* src = y_pred + ((size_t)img * NBOX + b0) * 25;
        int nf = nval * 25;
        for (int f = tid; f < nf; f += 256) st[f] = src[f];   // fully coalesced
    }
    __syncthreads();
    int i = b0 + tid;
    size_t o = (size_t)img * NPAD + i;
    if (tid < nval) {
        const float* yl = st + tid * 25;
        float best = yl[0]; int bi = 0;
        #pragma unroll
        for (int k = 1; k < NCLS; k++) { float v = yl[k]; if (v > best) { best = v; bi = k; } }
        float4 a = ((const float4*)box_tensor)[i];
        float t0 = yl[21], t1 = yl[22], t2 = yl[23], t3 = yl[24];
        float cx = __fadd_rn(__fmul_rn(__fmul_rn(t0, 0.1f), a.z), a.x);
        float cy = __fadd_rn(__fmul_rn(__fmul_rn(t1, 0.1f), a.w), a.y);
        float w  = __fmul_rn((float)exp((double)__fmul_rn(t2, 0.2f)), a.z);
        float h  = __fmul_rn((float)exp((double)__fmul_rn(t3, 0.2f)), a.w);
        float hw = __fmul_rn(0.5f, w), hh = __fmul_rn(0.5f, h);
        float xmin = fminf(fmaxf(__fsub_rn(cx, hw), 0.f), 1.f);
        float ymin = fminf(fmaxf(__fsub_rn(cy, hh), 0.f), 1.f);
        float xmax = fminf(fmaxf(__fadd_rn(cx, hw), 0.f), 1.f);
        float ymax = fminf(fmaxf(__fadd_rn(cy, hh), 0.f), 1.f);
        bool valid = (bi != 0) && (best > 0.01f);
        X0[o] = xmin; Y0[o] = ymin; X1[o] = xmax; Y1[o] = ymax; CL[o] = (float)bi;
        uint hi = valid ? key_hi(best) : __float_as_uint(NEGV);  // NEG: hi = raw bits (sign set)
        KS[o] = ((ull)hi << 32) | (uint)i;
    } else {
        X0[o] = 0.f; Y0[o] = 0.f; X1[o] = 0.f; Y1[o] = 0.f; CL[o] = 0.f;
        KS[o] = ((ull)__float_as_uint(NEGV) << 32) | (uint)i;
    }
}

// ---------------- Kernel B: per-segment bitonic sort of packed keys ----------------
__global__ __launch_bounds__(1024) void sort_kernel(ull* __restrict__ KS)
{
    __shared__ ull sk[SEGSZ];
    int seg = blockIdx.x, img = blockIdx.y;
    ull* base = KS + (size_t)img * NPAD + (size_t)seg * SEGSZ;
    int tid = threadIdx.x;
    sk[tid] = base[tid]; sk[tid + 1024] = base[tid + 1024];
    __syncthreads();
    for (int k = 2; k <= SEGSZ; k <<= 1) {
        for (int j = k >> 1; j > 0; j >>= 1) {
            int i = ((tid & ~(j - 1)) << 1) | (tid & (j - 1));
            int l = i | j;
            ull a = sk[i], b = sk[l];
            if ((a > b) == ((i & k) == 0)) { sk[i] = b; sk[l] = a; }
            __syncthreads();
        }
    }
    base[tid] = sk[tid]; base[tid + 1024] = sk[tid + 1024];
}

// ---------------- accept helper (shared by walk + fallback) ----------------
__device__ __forceinline__ void try_accept(
    int lane, int& A, float ax0[2], float ay0[2], float ax1[2], float ay1[2], float aar[2],
    float cx0, float cy0, float cx1, float cy1, float ccl, float score, float* orow)
{
    float carea = __fmul_rn(__fsub_rn(cx1, cx0), __fsub_rn(cy1, cy0));
    bool sup = false;
    #pragma unroll
    for (int t = 0; t < 2; t++) {
        int slot = lane + 64 * t;
        if (slot < A) {
            float ix1 = fmaxf(ax0[t], cx0);
            float iy1 = fmaxf(ay0[t], cy0);
            float ix2 = fminf(ax1[t], cx1);
            float iy2 = fminf(ay1[t], cy1);
            float inter = __fmul_rn(fmaxf(__fsub_rn(ix2, ix1), 0.f),
                                    fmaxf(__fsub_rn(iy2, iy1), 0.f));
            float uni = __fsub_rn(__fadd_rn(aar[t], carea), inter);
            float iou = (uni > 0.f) ? __fdiv_rn(inter, fmaxf(uni, 1e-12f)) : 0.f;
            if (iou > 0.45f) sup = true;
        }
    }
    if (__ballot(sup) != 0ull) return;
    if (lane == (A & 63)) {
        if ((A >> 6) == 0) { ax0[0]=cx0; ay0[0]=cy0; ax1[0]=cx1; ay1[0]=cy1; aar[0]=carea; }
        else               { ax0[1]=cx0; ay0[1]=cy0; ax1[1]=cx1; ay1[1]=cy1; aar[1]=carea; }
    }
    if (lane == 0) {
        orow[A * 6 + 0] = ccl; orow[A * 6 + 1] = score;
        orow[A * 6 + 2] = cx0; orow[A * 6 + 3] = cy0;
        orow[A * 6 + 4] = cx1; orow[A * 6 + 5] = cy1;
    }
    A++;
}

// ---------------- Kernel C: pre-merge top prefixes + linear NMS walk ----------------
__global__ __launch_bounds__(512) void nms_kernel(
    const ull* __restrict__ KS,
    const float* __restrict__ X0, const float* __restrict__ Y0,
    const float* __restrict__ X1, const float* __restrict__ Y1,
    const float* __restrict__ CL, float* __restrict__ out)
{
    __shared__ ull klist[MCAP];
    __shared__ ull pref[NSEG];
    __shared__ ull bkey[2][64];
    __shared__ float bb0[2][64], bb1[2][64], bb2[2][64], bb3[2][64], bb4[2][64];

    int img = blockIdx.x, tid = threadIdx.x;
    const ull* ksg = KS + (size_t)img * NPAD;

    // phase 1: stage per-segment prefixes
    for (int e = tid; e < MCAP; e += 512) {
        if (e < NWALK) {
            int seg = e / PFX, q = e - seg * PFX;
            klist[e] = ksg[seg * SEGSZ + q];
        } else klist[e] = ~0ull;
    }
    if (tid < NSEG) pref[tid] = ksg[tid * SEGSZ + PFX];  // first un-staged key per segment
    __syncthreads();

    // phase 2: bitonic sort MCAP keys ascending (exact global order below cutk)
    for (int k = 2; k <= MCAP; k <<= 1) {
        for (int j = k >> 1; j > 0; j >>= 1) {
            for (int t = tid; t < MCAP / 2; t += 512) {
                int i = ((t & ~(j - 1)) << 1) | (t & (j - 1));
                int l = i | j;
                ull a = klist[i], b = klist[l];
                if ((a > b) == ((i & k) == 0)) { klist[i] = b; klist[l] = a; }
            }
            __syncthreads();
        }
    }

    // phase 3: wave 0 walks in exact order with double-buffered LDS batch gather
    if (tid >= 64) return;
    int lane = tid;
    const float* x0g = X0 + (size_t)img * NPAD;
    const float* y0g = Y0 + (size_t)img * NPAD;
    const float* x1g = X1 + (size_t)img * NPAD;
    const float* y1g = Y1 + (size_t)img * NPAD;
    const float* clg = CL + (size_t)img * NPAD;
    float* orow = out + (size_t)img * 600;

    ull cutk = ~0ull;
    for (int s = 0; s < NSEG; s++) { ull v = pref[s]; if (v < cutk) cutk = v; }

    float ax0[2], ay0[2], ax1[2], ay1[2], aar[2];
    int A = 0;
    ull lastk = 0;
    int stop = 0, done = 0;

    // prefetch batch 0
    ull pk; float p0, p1, p2, p3, p4;
    {
        int c = lane;
        pk = (c < NWALK) ? klist[c] : ~0ull;
        uint hi = (uint)(pk >> 32); uint id = (uint)pk;
        if (!(hi & 0x80000000u)) { p0=x0g[id]; p1=y0g[id]; p2=x1g[id]; p3=y1g[id]; p4=clg[id]; }
        else { p0=p1=p2=p3=p4=0.f; }
    }
    int buf = 0;
    for (int base = 0; base < NWALK && !stop; base += 64) {
        bkey[buf][lane] = pk;
        bb0[buf][lane]=p0; bb1[buf][lane]=p1; bb2[buf][lane]=p2; bb3[buf][lane]=p3; bb4[buf][lane]=p4;
        {   // prefetch next batch while we walk this one
            int c = base + 64 + lane;
            pk = (c < NWALK) ? klist[c] : ~0ull;
            uint hi = (uint)(pk >> 32); uint id = (uint)pk;
            if (!(hi & 0x80000000u)) { p0=x0g[id]; p1=y0g[id]; p2=x1g[id]; p3=y1g[id]; p4=clg[id]; }
            else { p0=p1=p2=p3=p4=0.f; }
        }
        int nb = NWALK - base; if (nb > 64) nb = 64;
        for (int u = 0; u < nb; u++) {
            ull kk = bkey[buf][u];
            uint hi = (uint)(kk >> 32);
            if (hi & 0x80000000u) { stop = 1; done = 1; break; }  // invalid => all valid were staged
            if (kk >= cutk)       { stop = 1; done = 0; break; }  // order uncertain beyond cutk
            try_accept(lane, A, ax0, ay0, ax1, ay1, aar,
                       bb0[buf][u], bb1[buf][u], bb2[buf][u], bb3[buf][u], bb4[buf][u],
                       key_score(hi), orow);
            lastk = kk;
            if (A == 100) { stop = 1; done = 1; break; }
        }
        buf ^= 1;
    }
    if (!stop) done = (int)(cutk >> 63);  // exhausted staging; done iff all segments fully staged

    // correctness fallback (never expected to run): brute-force ordered pops from global
    if (!done && A < 100) {
        while (A < 100) {
            ull best = ~0ull;
            for (int e = lane; e < NPAD; e += 64) {
                ull kk = ksg[e];
                if (kk > lastk && kk < best) best = kk;
            }
            #pragma unroll
            for (int off = 32; off; off >>= 1) {
                ull o = __shfl_xor(best, off);
                if (o < best) best = o;
            }
            uint hi = (uint)(best >> 32);
            if (hi & 0x80000000u) break;
            lastk = best;
            uint id = (uint)best;
            try_accept(lane, A, ax0, ay0, ax1, ay1, aar,
                       x0g[id], y0g[id], x1g[id], y1g[id], clg[id], key_score(hi), orow);
        }
    }

    // zero-fill remaining rows
    for (int r = lane; r < (100 - A) * 6; r += 64) orow[A * 6 + r] = 0.f;
}

extern "C" void kernel_launch(void* const* d_in, const int* in_sizes, int n_in,
                              void* d_out, int out_size, void* d_ws, size_t ws_size,
                              hipStream_t stream)
{
    const float* y_pred     = (const float*)d_in[0];
    const float* box_tensor = (const float*)d_in[1];
    float* out = (float*)d_out;

    size_t stride = (size_t)BATCH * NPAD;
    ull*   KS = (ull*)d_ws;                       // 8B-aligned first
    float* X0 = (float*)(KS + stride);
    float* Y0 = X0 + stride;
    float* X1 = Y0 + stride;
    float* Y1 = X1 + stride;
    float* CL = Y1 + stride;

    decode_kernel<<<dim3(NPAD / 256, BATCH), 256, 0, stream>>>(
        y_pred, box_tensor, X0, Y0, X1, Y1, CL, KS);
    sort_kernel<<<dim3(NSEG, BATCH), 1024, 0, stream>>>(KS);
    nms_kernel<<<BATCH, 512, 0, stream>>>(KS, X0, Y0, X1, Y1, CL, out);
}

// Round 3
// 172.260 us; speedup vs baseline: 1.7410x; 1.2262x over previous
//
#include <hip/hip_runtime.h>
#include <math.h>

typedef unsigned long long ull;
typedef unsigned int uint;

#define NBOX 21840
#define NPAD 22528            // 44*512 = 88*256
#define NSEG 44
#define SEGSZ 512
#define PFXS 46               // staged per segment
#define OUTW 47               // 46 staged + 1 pref key
#define NWALK (NSEG*PFXS)     // 2024
#define MCAP 2048
#define BATCH 32
#define NCLS 21
#define NEGV -1e30f

// ---- sortable key: ascending u64 == (score desc, idx asc); lo = (idx<<8)|cls ----
__device__ __forceinline__ uint key_hi(float s) {
    uint b = __float_as_uint(s);
    uint m = (uint)((int)b >> 31) | 0x80000000u;
    return ~(b ^ m);                       // valid (s>0.01>0) => hi < 0x80000000
}
__device__ __forceinline__ float key_score(uint hi) {
    uint srt = ~hi;
    uint b = (srt & 0x80000000u) ? (srt ^ 0x80000000u) : ~srt;
    return __uint_as_float(b);
}

__device__ __forceinline__ float area_of(float4 b) {
    return __fmul_rn(__fsub_rn(b.z, b.x), __fsub_rn(b.w, b.y));
}
// iou with (suppressor area, candidate area) — bit-exact vs reference
__device__ __forceinline__ float iou_exact(float4 a, float aarea, float4 c, float carea) {
    float ix1 = fmaxf(a.x, c.x), iy1 = fmaxf(a.y, c.y);
    float ix2 = fminf(a.z, c.z), iy2 = fminf(a.w, c.w);
    float inter = __fmul_rn(fmaxf(__fsub_rn(ix2, ix1), 0.f), fmaxf(__fsub_rn(iy2, iy1), 0.f));
    float uni = __fsub_rn(__fadd_rn(aarea, carea), inter);
    return (uni > 0.f) ? __fdiv_rn(inter, fmaxf(uni, 1e-12f)) : 0.f;
}

// ---------------- Kernel A: decode ----------------
__global__ __launch_bounds__(256) void decode_kernel(
    const float* __restrict__ y_pred, const float* __restrict__ box_tensor,
    float4* __restrict__ BX, ull* __restrict__ KS)
{
    __shared__ float st[256 * 25];     // 25.6 KB
    int img = blockIdx.y;
    int b0  = blockIdx.x << 8;
    int tid = threadIdx.x;
    int nval = NBOX - b0; if (nval > 256) nval = 256;
    if (nval > 0) {
        const float* src = y_pred + ((size_t)img * NBOX + b0) * 25;
        int nf = nval * 25;
        for (int f = tid; f < nf; f += 256) st[f] = src[f];   // coalesced
    }
    __syncthreads();
    int i = b0 + tid;
    size_t o = (size_t)img * NPAD + i;
    if (tid < nval) {
        const float* yl = st + tid * 25;
        float best = yl[0]; int bi = 0;
        #pragma unroll
        for (int k = 1; k < NCLS; k++) { float v = yl[k]; if (v > best) { best = v; bi = k; } }
        float4 a = ((const float4*)box_tensor)[i];
        float t0 = yl[21], t1 = yl[22], t2 = yl[23], t3 = yl[24];
        float cx = __fadd_rn(__fmul_rn(__fmul_rn(t0, 0.1f), a.z), a.x);
        float cy = __fadd_rn(__fmul_rn(__fmul_rn(t1, 0.1f), a.w), a.y);
        float w  = __fmul_rn((float)exp((double)__fmul_rn(t2, 0.2f)), a.z);
        float h  = __fmul_rn((float)exp((double)__fmul_rn(t3, 0.2f)), a.w);
        float hw = __fmul_rn(0.5f, w), hh = __fmul_rn(0.5f, h);
        float xmin = fminf(fmaxf(__fsub_rn(cx, hw), 0.f), 1.f);
        float ymin = fminf(fmaxf(__fsub_rn(cy, hh), 0.f), 1.f);
        float xmax = fminf(fmaxf(__fadd_rn(cx, hw), 0.f), 1.f);
        float ymax = fminf(fmaxf(__fadd_rn(cy, hh), 0.f), 1.f);
        bool valid = (bi != 0) && (best > 0.01f);
        BX[o] = make_float4(xmin, ymin, xmax, ymax);
        uint hi = valid ? key_hi(best) : __float_as_uint(NEGV);
        KS[o] = ((ull)hi << 32) | ((uint)(i << 8)) | (uint)bi;
    } else {
        BX[o] = make_float4(0.f, 0.f, 0.f, 0.f);
        KS[o] = ((ull)__float_as_uint(NEGV) << 32) | ((uint)(i << 8));
    }
}

// ---------------- Kernel B: 512-elem segment bitonic sort, emit compact top-47 ----------------
__global__ __launch_bounds__(256) void sort_kernel(const ull* __restrict__ KS, ull* __restrict__ KS2)
{
    __shared__ ull sk[SEGSZ];
    int seg = blockIdx.x, img = blockIdx.y;
    const ull* base = KS + (size_t)img * NPAD + (size_t)seg * SEGSZ;
    int tid = threadIdx.x;
    sk[tid] = base[tid]; sk[tid + 256] = base[tid + 256];
    __syncthreads();
    for (int k = 2; k <= SEGSZ; k <<= 1) {
        for (int j = k >> 1; j > 0; j >>= 1) {
            int i = ((tid & ~(j - 1)) << 1) | (tid & (j - 1));
            int l = i | j;
            ull a = sk[i], b = sk[l];
            if ((a > b) == ((i & k) == 0)) { sk[i] = b; sk[l] = a; }
            __syncthreads();
        }
    }
    if (tid < OUTW) KS2[(size_t)img * (NSEG * OUTW) + seg * OUTW + tid] = sk[tid];
}

// ---------------- Kernel C: merge prefixes, sort 2048, batched greedy-NMS walk ----------------
__global__ __launch_bounds__(512) void nms_kernel(
    const ull* __restrict__ KS2, const ull* __restrict__ KS,
    const float4* __restrict__ BX, float* __restrict__ out)
{
    __shared__ ull klist[MCAP];        // 16 KB
    __shared__ ull pref[NSEG];
    __shared__ float4 bbox[64];
    __shared__ float4 accbox[100];
    __shared__ float  accarea[100];

    int img = blockIdx.x, tid = threadIdx.x;
    const ull* ks2i = KS2 + (size_t)img * (NSEG * OUTW);

    // stage 44 sorted prefixes of 46
    for (int e = tid; e < MCAP; e += 512) {
        ull v = ~0ull;
        if (e < NWALK) { int seg = e / PFXS, q = e - seg * PFXS; v = ks2i[seg * OUTW + q]; }
        klist[e] = v;
    }
    if (tid < NSEG) pref[tid] = ks2i[tid * OUTW + PFXS];
    __syncthreads();

    // bitonic sort 2048 ascending
    for (int k = 2; k <= MCAP; k <<= 1) {
        for (int j = k >> 1; j > 0; j >>= 1) {
            for (int t = tid; t < MCAP / 2; t += 512) {
                int i = ((t & ~(j - 1)) << 1) | (t & (j - 1));
                int l = i | j;
                ull a = klist[i], b = klist[l];
                if ((a > b) == ((i & k) == 0)) { klist[i] = b; klist[l] = a; }
            }
            __syncthreads();
        }
    }

    if (tid >= 64) return;        // walk: wave 0 only
    int lane = tid;
    const float4* BXg = BX + (size_t)img * NPAD;
    const ull*    ksg = KS + (size_t)img * NPAD;
    float* orow = out + (size_t)img * 600;

    ull cutk = ~0ull;
    for (int s = 0; s < NSEG; s++) { ull v = pref[s]; if (v < cutk) cutk = v; }

    int A = 0, stop = 0, done = 0;

    // prefetch batch 0
    ull pk = klist[lane];
    float4 pbox = make_float4(0.f, 0.f, 0.f, 0.f);
    if (!(pk >> 63)) pbox = BXg[((uint)pk) >> 8];

    for (int base = 0; base < MCAP && !stop; base += 64) {
        ull kk = pk; float4 bb = pbox;
        {   // prefetch next batch
            int c = base + 64 + lane;
            pk = (c < MCAP) ? klist[c] : ~0ull;
            if (!(pk >> 63)) pbox = BXg[((uint)pk) >> 8];
        }
        uint hi = (uint)(kk >> 32);
        uint lo = (uint)kk;
        bool valid = !(kk >> 63) && (kk < cutk);
        ull vmask = __ballot(valid);

        bbox[lane] = bb;
        float mya = area_of(bb);

        // suppressed by prior accepted?
        bool p = false;
        for (int a = 0; a < A; a++) {
            float4 ab = accbox[a];
            if (iou_exact(ab, accarea[a], bb, mya) > 0.45f) p = true;
        }
        // within-batch suppressor mask (earlier lanes only)
        ull sup = 0;
        for (int j = 0; j < 64; j++) {
            float4 bj = bbox[j];
            float aj = area_of(bj);
            if (iou_exact(bj, aj, bb, mya) > 0.45f) sup |= (1ull << j);
        }
        sup &= vmask & ((lane == 0) ? 0ull : ((~0ull) >> (64 - lane)));

        ull cand = __ballot(valid && !p);
        while (cand && A < 100) {
            int i = __ffsll(cand) - 1;
            ull sup_by_i = __ballot((sup >> i) & 1ull);
            if (lane == i) {
                accbox[A] = bb; accarea[A] = mya;
                orow[A * 6 + 0] = (float)(lo & 0xffu);
                orow[A * 6 + 1] = key_score(hi);
                orow[A * 6 + 2] = bb.x; orow[A * 6 + 3] = bb.y;
                orow[A * 6 + 4] = bb.z; orow[A * 6 + 5] = bb.w;
            }
            A++;
            cand &= ~(1ull << i);
            cand &= ~sup_by_i;
        }
        if (A >= 100) { stop = 1; done = 1; }
        else if (vmask != ~0ull) {
            stop = 1;
            int fi = __ffsll(~vmask) - 1;
            ull fk = __shfl(kk, fi);
            done = (fk >= cutk) ? (int)(cutk >> 63) : 1;
        }
        __builtin_amdgcn_wave_barrier();
    }

    // fallback (expected dead): ordered pops over full key array from nextk=cutk
    if (!done && A < 100) {
        ull nextk = cutk;
        while (A < 100) {
            ull best = ~0ull;
            for (int e = lane; e < NPAD; e += 64) {
                ull kk2 = ksg[e];
                if (kk2 >= nextk && kk2 < best) best = kk2;
            }
            #pragma unroll
            for (int off = 32; off; off >>= 1) {
                ull o = __shfl_xor(best, off);
                if (o < best) best = o;
            }
            if (best >> 63) break;
            uint bhi = (uint)(best >> 32), blo = (uint)best;
            float4 cb = BXg[blo >> 8];
            float ca = area_of(cb);
            bool sup2 = false;
            #pragma unroll
            for (int t = 0; t < 2; t++) {
                int slot = lane + 64 * t;
                if (slot < A) {
                    if (iou_exact(accbox[slot], accarea[slot], cb, ca) > 0.45f) sup2 = true;
                }
            }
            if (__ballot(sup2) == 0ull) {
                if (lane == 0) {
                    accbox[A] = cb; accarea[A] = ca;
                    orow[A * 6 + 0] = (float)(blo & 0xffu);
                    orow[A * 6 + 1] = key_score(bhi);
                    orow[A * 6 + 2] = cb.x; orow[A * 6 + 3] = cb.y;
                    orow[A * 6 + 4] = cb.z; orow[A * 6 + 5] = cb.w;
                }
                A++;
            }
            nextk = best + 1;
            __builtin_amdgcn_wave_barrier();
        }
    }

    for (int r = lane; r < (100 - A) * 6; r += 64) orow[A * 6 + r] = 0.f;
}

extern "C" void kernel_launch(void* const* d_in, const int* in_sizes, int n_in,
                              void* d_out, int out_size, void* d_ws, size_t ws_size,
                              hipStream_t stream)
{
    const float* y_pred     = (const float*)d_in[0];
    const float* box_tensor = (const float*)d_in[1];
    float* out = (float*)d_out;

    size_t stride = (size_t)BATCH * NPAD;
    ull*    KS  = (ull*)d_ws;                       // 5.77 MB
    float4* BX  = (float4*)(KS + stride);           // 11.53 MB
    ull*    KS2 = (ull*)(BX + stride);              // 0.53 MB

    decode_kernel<<<dim3(NPAD / 256, BATCH), 256, 0, stream>>>(y_pred, box_tensor, BX, KS);
    sort_kernel<<<dim3(NSEG, BATCH), 256, 0, stream>>>(KS, KS2);
    nms_kernel<<<BATCH, 512, 0, stream>>>(KS2, KS, BX, out);
}

// Round 4
// 154.902 us; speedup vs baseline: 1.9360x; 1.1121x over previous
//
#include <hip/hip_runtime.h>
#include <math.h>

typedef unsigned long long ull;
typedef unsigned int uint;

#define NBOX 21840
#define SEGSZ 512
#define NSEG 44
#define NPAD (NSEG*SEGSZ)     // 22528
#define PFXS 46               // staged per segment
#define OUTW 47               // 46 staged + 1 pref key
#define NWALK (NSEG*PFXS)     // 2024
#define MCAP 2048
#define BATCH 32
#define NCLS 21
#define NEGV -1e30f
// midpoint(0.45f, nextafterf(0.45f)) = 15099494.5 * 2^-25, exactly representable.
// RN(inter/u) > 0.45f  <=>  (double)inter > MIOU * (double)u   (u > 0)
#define MIOU (15099494.5/33554432.0)

// ---- sortable key: ascending u64 == (score desc, idx asc); lo = (idx<<8)|cls ----
__device__ __forceinline__ uint key_hi(float s) {
    uint b = __float_as_uint(s);
    uint m = (uint)((int)b >> 31) | 0x80000000u;
    return ~(b ^ m);                       // valid (s>0.01>0) => hi < 0x80000000
}
__device__ __forceinline__ float key_score(uint hi) {
    uint srt = ~hi;
    uint b = (srt & 0x80000000u) ? (srt ^ 0x80000000u) : ~srt;
    return __uint_as_float(b);
}

__device__ __forceinline__ float area_of(float4 b) {
    return __fmul_rn(__fsub_rn(b.z, b.x), __fsub_rn(b.w, b.y));
}
// exact iou>0.45 decision, divide-free (proof: strict > at midpoint; tie rounds to even=0.45f)
__device__ __forceinline__ bool sup_check(float4 a, float aarea, float4 c, float carea) {
    float ix1 = fmaxf(a.x, c.x), iy1 = fmaxf(a.y, c.y);
    float ix2 = fminf(a.z, c.z), iy2 = fminf(a.w, c.w);
    float inter = __fmul_rn(fmaxf(__fsub_rn(ix2, ix1), 0.f), fmaxf(__fsub_rn(iy2, iy1), 0.f));
    float uni = __fsub_rn(__fadd_rn(aarea, carea), inter);
    return (uni > 0.f) && ((double)inter > MIOU * (double)fmaxf(uni, 1e-12f));
}

// one bitonic compare-exchange pass with j<=32: partner is in-wave, via shfl
__device__ __forceinline__ ull cex_shfl(ull v, int j, bool asc, int lane) {
    ull pv = __shfl_xor(v, j);
    bool keepmin = (((lane & j) == 0) == asc);
    bool less = (v < pv);
    return (keepmin == less) ? v : pv;
}

// ---------------- Kernel A: fused decode + per-segment sort (512 boxes/block) ----------------
__global__ __launch_bounds__(512) void decode_sort_kernel(
    const float* __restrict__ y_pred, const float* __restrict__ box_tensor,
    float4* __restrict__ BX, ull* __restrict__ KS, ull* __restrict__ KS2)
{
    __shared__ float st[SEGSZ * 25];   // 51.2 KB
    __shared__ ull sk[SEGSZ];          // 4 KB
    int img = blockIdx.y, seg = blockIdx.x, tid = threadIdx.x;
    int b0 = seg * SEGSZ;
    int nval = NBOX - b0; nval = nval < 0 ? 0 : (nval > SEGSZ ? SEGSZ : nval);
    if (nval > 0) {
        const float* src = y_pred + ((size_t)img * NBOX + b0) * 25;
        int nf = nval * 25, nf4 = nf >> 2;
        const float4* src4 = (const float4*)src;
        float4* st4 = (float4*)st;
        for (int f = tid; f < nf4; f += 512) st4[f] = src4[f];
        for (int f = (nf4 << 2) + tid; f < nf; f += 512) st[f] = src[f];
    }
    __syncthreads();
    int i = b0 + tid;
    size_t o = (size_t)img * NPAD + i;
    ull v;
    if (tid < nval) {
        const float* yl = st + tid * 25;
        float best = yl[0]; int bi = 0;
        #pragma unroll
        for (int k = 1; k < NCLS; k++) { float x = yl[k]; if (x > best) { best = x; bi = k; } }
        float4 a = ((const float4*)box_tensor)[i];
        float t0 = yl[21], t1 = yl[22], t2 = yl[23], t3 = yl[24];
        float cx = __fadd_rn(__fmul_rn(__fmul_rn(t0, 0.1f), a.z), a.x);
        float cy = __fadd_rn(__fmul_rn(__fmul_rn(t1, 0.1f), a.w), a.y);
        float w  = __fmul_rn((float)exp((double)__fmul_rn(t2, 0.2f)), a.z);
        float h  = __fmul_rn((float)exp((double)__fmul_rn(t3, 0.2f)), a.w);
        float hw = __fmul_rn(0.5f, w), hh = __fmul_rn(0.5f, h);
        float xmin = fminf(fmaxf(__fsub_rn(cx, hw), 0.f), 1.f);
        float ymin = fminf(fmaxf(__fsub_rn(cy, hh), 0.f), 1.f);
        float xmax = fminf(fmaxf(__fadd_rn(cx, hw), 0.f), 1.f);
        float ymax = fminf(fmaxf(__fadd_rn(cy, hh), 0.f), 1.f);
        bool valid = (bi != 0) && (best > 0.01f);
        BX[o] = make_float4(xmin, ymin, xmax, ymax);
        uint hi = valid ? key_hi(best) : __float_as_uint(NEGV);
        v = ((ull)hi << 32) | ((uint)(i << 8)) | (uint)bi;
    } else {
        v = ((ull)__float_as_uint(NEGV) << 32) | ((uint)(i << 8));
    }
    // hybrid bitonic sort of 512 keys: j>=64 via LDS, j<=32 via shfl (no barrier)
    int lane = tid & 63;
    for (int k = 2; k <= SEGSZ; k <<= 1) {
        for (int j = k >> 1; j >= 64; j >>= 1) {
            sk[tid] = v; __syncthreads();
            ull pv = sk[tid ^ j];
            bool keepmin = (((tid & j) == 0) == ((tid & k) == 0));
            bool less = (v < pv);
            v = (keepmin == less) ? v : pv;
            __syncthreads();
        }
        int j0 = (k >> 1) < 32 ? (k >> 1) : 32;
        for (int j = j0; j >= 1; j >>= 1)
            v = cex_shfl(v, j, (tid & k) == 0, lane);
    }
    KS[(size_t)img * NPAD + b0 + tid] = v;                              // sorted segment (fallback)
    if (tid < OUTW) KS2[(size_t)img * (NSEG * OUTW) + seg * OUTW + tid] = v;
}

// ---------------- Kernel B: merge prefixes (hybrid 2048 sort) + batched greedy walk ----------------
__global__ __launch_bounds__(512) void nms_kernel(
    const ull* __restrict__ KS2, const ull* __restrict__ KS,
    const float4* __restrict__ BX, float* __restrict__ out)
{
    __shared__ ull klist[MCAP];        // 16 KB
    __shared__ ull pref[NSEG];
    __shared__ float4 accbox[100];
    __shared__ float  accarea[100];

    int img = blockIdx.x, tid = threadIdx.x;
    int wid = tid >> 6, lane = tid & 63;
    const ull* ks2i = KS2 + (size_t)img * (NSEG * OUTW);

    // stage 44 sorted prefixes of 46 into registers (element e = wid*256 + r*64 + lane)
    ull v[4];
    #pragma unroll
    for (int r = 0; r < 4; r++) {
        int e = (wid << 8) + (r << 6) + lane;
        v[r] = (e < NWALK) ? ks2i[(e / PFXS) * OUTW + (e % PFXS)] : ~0ull;
    }
    if (tid < NSEG) pref[tid] = ks2i[tid * OUTW + PFXS];

    // hybrid bitonic sort 2048 ascending
    for (int k = 2; k <= MCAP; k <<= 1) {
        int jl = k >> 1;
        if (jl >= 64) {
            #pragma unroll
            for (int r = 0; r < 4; r++) klist[(wid << 8) + (r << 6) + lane] = v[r];
            for (int j = jl; j >= 64; j >>= 1) {
                __syncthreads();
                for (int t = tid; t < MCAP / 2; t += 512) {
                    int i = ((t & ~(j - 1)) << 1) | (t & (j - 1));
                    int l = i | j;
                    ull a = klist[i], b = klist[l];
                    if ((a > b) == ((i & k) == 0)) { klist[i] = b; klist[l] = a; }
                }
            }
            __syncthreads();
            #pragma unroll
            for (int r = 0; r < 4; r++) v[r] = klist[(wid << 8) + (r << 6) + lane];
        }
        int j0 = jl < 32 ? jl : 32;
        for (int j = j0; j >= 1; j >>= 1) {
            #pragma unroll
            for (int r = 0; r < 4; r++) {
                int e = (wid << 8) + (r << 6) + lane;
                v[r] = cex_shfl(v[r], j, (e & k) == 0, lane);
            }
        }
    }
    #pragma unroll
    for (int r = 0; r < 4; r++) klist[(wid << 8) + (r << 6) + lane] = v[r];
    __syncthreads();

    if (tid >= 64) return;             // walk: wave 0 only
    const float4* BXg = BX + (size_t)img * NPAD;
    const ull*    ksg = KS + (size_t)img * NPAD;
    float* orow = out + (size_t)img * 600;

    ull cutk = ~0ull;
    for (int s = 0; s < NSEG; s++) { ull x = pref[s]; if (x < cutk) cutk = x; }

    int A = 0, stop = 0, done = 0;

    // prefetch batch 0
    ull pk = klist[lane];
    float4 pbox = make_float4(0.f, 0.f, 0.f, 0.f);
    if (!(pk >> 63)) pbox = BXg[((uint)pk) >> 8];

    for (int base = 0; base < MCAP && !stop; base += 64) {
        ull kk = pk; float4 bb = pbox;
        {   // prefetch next batch
            int c = base + 64 + lane;
            pk = (c < MCAP) ? klist[c] : ~0ull;
            pbox = make_float4(0.f, 0.f, 0.f, 0.f);
            if (!(pk >> 63)) pbox = BXg[((uint)pk) >> 8];
        }
        bool valid = !(kk >> 63) && (kk < cutk);
        ull vmask = __ballot(valid);
        float carea = area_of(bb);

        // suppressed by prior accepted? (LDS broadcast loop, all lanes in parallel)
        bool p = false;
        for (int a = 0; a < A; a++)
            p = p || sup_check(accbox[a], accarea[a], bb, carea);

        ull cand = __ballot(valid && !p);
        while (cand && A < 100) {
            int i = __ffsll((ull)cand) - 1;
            // broadcast accepted candidate's box, compute its suppressor row on the fly
            float4 ib = make_float4(__shfl(bb.x, i), __shfl(bb.y, i),
                                    __shfl(bb.z, i), __shfl(bb.w, i));
            float ia = __shfl(carea, i);
            ull row = __ballot(sup_check(ib, ia, bb, carea));
            if (lane == i) {
                accbox[A] = bb; accarea[A] = carea;
                uint hi = (uint)(kk >> 32), lo = (uint)kk;
                orow[A * 6 + 0] = (float)(lo & 0xffu);
                orow[A * 6 + 1] = key_score(hi);
                orow[A * 6 + 2] = bb.x; orow[A * 6 + 3] = bb.y;
                orow[A * 6 + 4] = bb.z; orow[A * 6 + 5] = bb.w;
            }
            A++;
            cand &= ~(1ull << i);
            cand &= ~row;
        }
        if (A >= 100) { stop = 1; done = 1; }
        else if (vmask != ~0ull) {
            stop = 1;
            int fi = __ffsll((ull)~vmask) - 1;
            ull fk = __shfl(kk, fi);
            done = (fk >= cutk) ? (int)(cutk >> 63) : 1;   // NEG first-fail => truly exhausted
        }
        __builtin_amdgcn_wave_barrier();
    }
    if (!stop) done = (int)(cutk >> 63);

    // correctness fallback (expected dead): ordered pops over full key array from cutk
    if (!done && A < 100) {
        ull nextk = cutk;
        while (A < 100) {
            ull best = ~0ull;
            for (int e = lane; e < NPAD; e += 64) {
                ull kk2 = ksg[e];
                if (kk2 >= nextk && kk2 < best) best = kk2;
            }
            #pragma unroll
            for (int off = 32; off; off >>= 1) {
                ull oo = __shfl_xor(best, off);
                if (oo < best) best = oo;
            }
            if (best >> 63) break;
            uint bhi = (uint)(best >> 32), blo = (uint)best;
            float4 cb = BXg[blo >> 8];
            float ca = area_of(cb);
            bool sup2 = false;
            #pragma unroll
            for (int t = 0; t < 2; t++) {
                int slot = lane + 64 * t;
                if (slot < A && sup_check(accbox[slot], accarea[slot], cb, ca)) sup2 = true;
            }
            if (__ballot(sup2) == 0ull) {
                if (lane == 0) {
                    accbox[A] = cb; accarea[A] = ca;
                    orow[A * 6 + 0] = (float)(blo & 0xffu);
                    orow[A * 6 + 1] = key_score(bhi);
                    orow[A * 6 + 2] = cb.x; orow[A * 6 + 3] = cb.y;
                    orow[A * 6 + 4] = cb.z; orow[A * 6 + 5] = cb.w;
                }
                A++;
            }
            nextk = best + 1;
            __builtin_amdgcn_wave_barrier();
        }
    }

    for (int r = lane; r < (100 - A) * 6; r += 64) orow[A * 6 + r] = 0.f;
}

extern "C" void kernel_launch(void* const* d_in, const int* in_sizes, int n_in,
                              void* d_out, int out_size, void* d_ws, size_t ws_size,
                              hipStream_t stream)
{
    const float* y_pred     = (const float*)d_in[0];
    const float* box_tensor = (const float*)d_in[1];
    float* out = (float*)d_out;

    size_t stride = (size_t)BATCH * NPAD;
    ull*    KS  = (ull*)d_ws;                       // 5.77 MB
    float4* BX  = (float4*)(KS + stride);           // 11.53 MB
    ull*    KS2 = (ull*)(BX + stride);              // 0.53 MB

    decode_sort_kernel<<<dim3(NSEG, BATCH), 512, 0, stream>>>(y_pred, box_tensor, BX, KS, KS2);
    nms_kernel<<<BATCH, 512, 0, stream>>>(KS2, KS, BX, out);
}